// Round 6
// baseline (67653.217 us; speedup 1.0000x reference)
//
#include <hip/hip_runtime.h>
#include <math.h>

// GRU RNN: T=32768, 2 layers H=512, in=128, out=128, fp32.
// v5 = v4 (fused 2-layer pipelined 48-block persistent scan) +
//   (a) call-free transcendentals (__expf-based sigmoid/tanh), and
//   (b) inline-asm anchors pinning the 72 weight float4s in VGPRs
//       (v4 showed VGPR_Count=84 < 96 weight regs -> the allocator was
//        re-streaming weights from L2 every step; ~1400 cyc/step).
//   L1: 16 blocks x 32 rows, k=512  -> 24 float4 weights/thread
//   L2: 32 blocks x 16 rows, k=1024 -> 24 float4 weights/thread (concat input)
// L1 -> L2 handoff: full-chunk tagged ring (ring1[C][512], tag = global step).
// L2 peer exchange: depth-4 tagged ring. Tags can't collide with 0xAA poison;
// rings memset as insurance. Per chunk: ig0 GEMM -> fused scan -> out GEMM.
// (Round 5 resubmission: round-5 bench was a GPU-acquisition timeout, v5
// never measured. No changes vs the round-4 submission.)

#define TSTEPS 32768
#define HDIM   512
#define G3     1536
#define NB1    16          // layer-1 blocks
#define NB2    32          // layer-2 blocks
#define S1     32          // rows per L1 block
#define S2     16          // rows per L2 block
#define RING2  4

// Call-free gate functions (saturation-safe at +/-inf, no NaN):
__device__ __forceinline__ float sigf(float x) {
  return 1.f / (1.f + __expf(-x));
}
__device__ __forceinline__ float tanhfast(float x) {
  const float E = __expf(2.f * x);        // inf -> 1-0=1 ; 0 -> 1-2=-1
  return 1.f - 2.f / (E + 1.f);
}
// Pin a float4 in VGPRs: opaque to remat, zero runtime cost.
__device__ __forceinline__ void pin4(float4& v) {
  asm volatile("" : "+v"(v.x), "+v"(v.y), "+v"(v.z), "+v"(v.w));
}

// ---------------------------------------------------------------------------
// GEMM: C[M,N] = A[M,K] * B[N,K]^T + bias[N].  BM=128 BN=64 BK=16, 256 thr.
// ---------------------------------------------------------------------------
template<int K>
__global__ __launch_bounds__(256)
void gemm_tn(const float* __restrict__ A, const float* __restrict__ B,
             const float* __restrict__ bias, float* __restrict__ C, int N) {
  __shared__ float As[16][128];
  __shared__ float Bs[16][64];
  const int bm  = blockIdx.x * 128;
  const int bn  = blockIdx.y * 64;
  const int tid = threadIdx.x;
  const int tx  = tid & 15;
  const int ty  = tid >> 4;
  const int lr  = tid >> 2;
  const int lk  = tid & 3;

  float acc[8][4];
#pragma unroll
  for (int i = 0; i < 8; ++i)
#pragma unroll
    for (int jj = 0; jj < 4; ++jj) acc[i][jj] = 0.f;

  for (int k0 = 0; k0 < K; k0 += 16) {
    float4 a0 = *(const float4*)&A[(size_t)(bm + lr) * K + k0 + lk * 4];
    float4 a1 = *(const float4*)&A[(size_t)(bm + lr + 64) * K + k0 + lk * 4];
    float4 bb = *(const float4*)&B[(size_t)(bn + lr) * K + k0 + lk * 4];
    __syncthreads();
    As[lk*4+0][lr]    = a0.x; As[lk*4+1][lr]    = a0.y;
    As[lk*4+2][lr]    = a0.z; As[lk*4+3][lr]    = a0.w;
    As[lk*4+0][lr+64] = a1.x; As[lk*4+1][lr+64] = a1.y;
    As[lk*4+2][lr+64] = a1.z; As[lk*4+3][lr+64] = a1.w;
    Bs[lk*4+0][lr] = bb.x; Bs[lk*4+1][lr] = bb.y;
    Bs[lk*4+2][lr] = bb.z; Bs[lk*4+3][lr] = bb.w;
    __syncthreads();
#pragma unroll
    for (int kk = 0; kk < 16; ++kk) {
      float4 b4  = *(const float4*)&Bs[kk][tx*4];
      float4 av0 = *(const float4*)&As[kk][ty*8];
      float4 av1 = *(const float4*)&As[kk][ty*8+4];
      float av[8] = {av0.x,av0.y,av0.z,av0.w,av1.x,av1.y,av1.z,av1.w};
#pragma unroll
      for (int i = 0; i < 8; ++i) {
        acc[i][0] += av[i]*b4.x; acc[i][1] += av[i]*b4.y;
        acc[i][2] += av[i]*b4.z; acc[i][3] += av[i]*b4.w;
      }
    }
  }
  float4 bv = *(const float4*)&bias[bn + tx*4];
#pragma unroll
  for (int i = 0; i < 8; ++i) {
    float4 o;
    o.x = acc[i][0] + bv.x; o.y = acc[i][1] + bv.y;
    o.z = acc[i][2] + bv.z; o.w = acc[i][3] + bv.w;
    *(float4*)&C[(size_t)(bm + ty*8 + i) * N + bn + tx*4] = o;
  }
}

// ---------------------------------------------------------------------------
// Fused 2-layer pipelined scan. Grid = NB1 + NB2 = 48 blocks x 512 threads.
// ---------------------------------------------------------------------------
__global__ __launch_bounds__(512, 2)
void gru2_scan(const float* __restrict__ ig0,   // [C][1536] layer-1 igates
               const float* __restrict__ Whh0,  // [1536][512]
               const float* __restrict__ bn0,   // [512]
               const float* __restrict__ Wih1,  // [1536][512]
               const float* __restrict__ Whh1,  // [1536][512]
               const float* __restrict__ b1v,   // [1536]
               const float* __restrict__ bn1,   // [512]
               float* __restrict__ h1carry,     // [512] cross-chunk carry
               float* __restrict__ h2c,         // [C][512] layer-2 history
               unsigned long long* __restrict__ ring1, // [C][512]
               unsigned long long* __restrict__ ring2, // [RING2][512]
               int C, unsigned t0, int first)
{
  const int tid = threadIdx.x;
  __shared__ __align__(16) float u[2][1024];   // L1 uses [.][0..511]
  __shared__ float igl[2][96];

  if (blockIdx.x < NB1) {
    // =================== layer 1 ===================
    const int b  = blockIdx.x;
    const int j  = tid >> 4;        // 0..31 row in slice
    const int g  = tid & 15;        // k-group (32 floats)
    const int jg = b * S1 + j;
    float4 wr[8], wz[8], wn[8];
    {
      const float* Wr = Whh0 + (size_t)jg            * HDIM + g * 32;
      const float* Wz = Whh0 + (size_t)(HDIM  + jg)  * HDIM + g * 32;
      const float* Wn = Whh0 + (size_t)(2*HDIM + jg) * HDIM + g * 32;
#pragma unroll
      for (int i = 0; i < 8; ++i) {
        const int c = (i + g) & 7;            // rotation: 2-way banks (free)
        wr[i] = *(const float4*)(Wr + c * 4);
        wz[i] = *(const float4*)(Wz + c * 4);
        wn[i] = *(const float4*)(Wn + c * 4);
      }
    }
#pragma unroll
    for (int i = 0; i < 8; ++i) { pin4(wr[i]); pin4(wz[i]); pin4(wn[i]); }
    const float bnj = bn0[jg];
    u[0][tid] = first ? 0.f : h1carry[tid];
    if (tid < 96)
      igl[0][tid] = ig0[(size_t)(tid >> 5) * HDIM + b * S1 + (tid & 31)];
    const int pm = (tid < b * S1) ? tid : tid + S1;   // 480 pollers
    __syncthreads();

    int p = 0;
    for (int t = 0; t < C; ++t) {
      float pfn = 0.f;
      if (tid < 96 && t + 1 < C)
        pfn = ig0[(size_t)(t + 1) * G3 + (size_t)(tid >> 5) * HDIM
                  + b * S1 + (tid & 31)];

      const float4* h4 = (const float4*)u[p];
      float4 ar = make_float4(0,0,0,0), az = make_float4(0,0,0,0),
             an = make_float4(0,0,0,0);
#pragma unroll
      for (int i = 0; i < 8; ++i) {
        const int c = (i + g) & 7;
        const float4 hv = h4[g * 8 + c];
        ar.x += wr[i].x*hv.x; ar.y += wr[i].y*hv.y; ar.z += wr[i].z*hv.z; ar.w += wr[i].w*hv.w;
        az.x += wz[i].x*hv.x; az.y += wz[i].y*hv.y; az.z += wz[i].z*hv.z; az.w += wz[i].w*hv.w;
        an.x += wn[i].x*hv.x; an.y += wn[i].y*hv.y; an.z += wn[i].z*hv.z; an.w += wn[i].w*hv.w;
      }
      float sr = (ar.x + ar.y) + (ar.z + ar.w);
      float sz = (az.x + az.y) + (az.z + az.w);
      float sn = (an.x + an.y) + (an.z + an.w);
      sr += __shfl_xor(sr,1); sr += __shfl_xor(sr,2); sr += __shfl_xor(sr,4); sr += __shfl_xor(sr,8);
      sz += __shfl_xor(sz,1); sz += __shfl_xor(sz,2); sz += __shfl_xor(sz,4); sz += __shfl_xor(sz,8);
      sn += __shfl_xor(sn,1); sn += __shfl_xor(sn,2); sn += __shfl_xor(sn,4); sn += __shfl_xor(sn,8);

      const unsigned tag = t0 + (unsigned)t + 1u;
      if (g == 0) {
        const float* igc = igl[t & 1];
        const float r = sigf(igc[j]      + sr);
        const float z = sigf(igc[32 + j] + sz);
        const float n = tanhfast(igc[64 + j] + r * (sn + bnj));
        const float hnew = n + z * (u[p][jg] - n);
        __hip_atomic_store(&ring1[(size_t)t * HDIM + jg],
            ((unsigned long long)tag << 32) | (unsigned)__float_as_uint(hnew),
            __ATOMIC_RELAXED, __HIP_MEMORY_SCOPE_AGENT);
        u[p ^ 1][jg] = hnew;
        if (t == C - 1) h1carry[jg] = hnew;
      }
      if (tid < 96 && t + 1 < C) igl[(t + 1) & 1][tid] = pfn;

      if (tid < HDIM - S1) {                    // gather peers' h1[t]
        unsigned long long vv;
        do {
          vv = __hip_atomic_load(&ring1[(size_t)t * HDIM + pm],
                                 __ATOMIC_RELAXED, __HIP_MEMORY_SCOPE_AGENT);
        } while ((unsigned)(vv >> 32) != tag);
        u[p ^ 1][pm] = __uint_as_float((unsigned)vv);
      }
      __syncthreads();
      p ^= 1;
    }
  } else {
    // =================== layer 2 ===================
    const int b  = blockIdx.x - NB1;
    const int j  = tid >> 5;        // 0..15 row in slice
    const int g  = tid & 31;        // k-group (32 of 1024 floats)
    const int jg = b * S2 + j;
    float4 wr[8], wz[8], wn[8];
    {
      const float* base = (g < 16) ? Wih1 : Whh1;   // concat [h1 || h2] k-split
      const int gk = (g & 15) * 32;
      const float* Wr = base + (size_t)jg            * HDIM + gk;
      const float* Wz = base + (size_t)(HDIM  + jg)  * HDIM + gk;
      const float* Wn = base + (size_t)(2*HDIM + jg) * HDIM + gk;
#pragma unroll
      for (int i = 0; i < 8; ++i) {
        const int c = (i + g) & 7;
        wr[i] = *(const float4*)(Wr + c * 4);
        wz[i] = *(const float4*)(Wz + c * 4);
        wn[i] = *(const float4*)(Wn + c * 4);
      }
    }
#pragma unroll
    for (int i = 0; i < 8; ++i) { pin4(wr[i]); pin4(wz[i]); pin4(wn[i]); }
    const float b1r = b1v[jg], b1z = b1v[HDIM + jg], b1n = b1v[2*HDIM + jg];
    const float bnj = bn1[jg];

    // init: u[0] = [h1[0] (poll) || h2 carry]
    u[0][512 + tid] = first ? 0.f : h2c[(size_t)(C - 1) * HDIM + tid];
    {
      unsigned long long vv;
      do {
        vv = __hip_atomic_load(&ring1[tid], __ATOMIC_RELAXED,
                               __HIP_MEMORY_SCOPE_AGENT);
      } while ((unsigned)(vv >> 32) != t0 + 1u);
      u[0][tid] = __uint_as_float((unsigned)vv);
    }
    const int pm2 = (tid < b * S2) ? tid : tid + S2;  // 496 pollers
    __syncthreads();

    int p = 0;
    for (int t = 0; t < C; ++t) {
      const float4* u4 = (const float4*)u[p];
      float4 ar = make_float4(0,0,0,0), az = make_float4(0,0,0,0),
             an = make_float4(0,0,0,0);
#pragma unroll
      for (int i = 0; i < 8; ++i) {
        const int c = (i + g) & 7;
        const float4 hv = u4[g * 8 + c];
        ar.x += wr[i].x*hv.x; ar.y += wr[i].y*hv.y; ar.z += wr[i].z*hv.z; ar.w += wr[i].w*hv.w;
        az.x += wz[i].x*hv.x; az.y += wz[i].y*hv.y; az.z += wz[i].z*hv.z; az.w += wz[i].w*hv.w;
        an.x += wn[i].x*hv.x; an.y += wn[i].y*hv.y; an.z += wn[i].z*hv.z; an.w += wn[i].w*hv.w;
      }
      float sr = (ar.x + ar.y) + (ar.z + ar.w);
      float sz = (az.x + az.y) + (az.z + az.w);
      float sn = (an.x + an.y) + (an.z + an.w);
      // r,z: full 32-lane sum. n: keep ih half (g<16) and hh half separate.
      sr += __shfl_xor(sr,1); sr += __shfl_xor(sr,2); sr += __shfl_xor(sr,4); sr += __shfl_xor(sr,8);
      sz += __shfl_xor(sz,1); sz += __shfl_xor(sz,2); sz += __shfl_xor(sz,4); sz += __shfl_xor(sz,8);
      sn += __shfl_xor(sn,1); sn += __shfl_xor(sn,2); sn += __shfl_xor(sn,4); sn += __shfl_xor(sn,8);
      sr += __shfl_xor(sr, 16);
      sz += __shfl_xor(sz, 16);
      const float snb = __shfl_xor(sn, 16);   // at g==0: hh-half sum

      const unsigned tag = t0 + (unsigned)t + 1u;
      if (g == 0) {
        const float r = sigf(sr + b1r);
        const float z = sigf(sz + b1z);
        const float n = tanhfast((sn + b1n) + r * (snb + bnj));
        const float hnew = n + z * (u[p][512 + jg] - n);
        h2c[(size_t)t * HDIM + jg] = hnew;
        __hip_atomic_store(&ring2[(size_t)((t & (RING2-1)) << 9) + jg],
            ((unsigned long long)tag << 32) | (unsigned)__float_as_uint(hnew),
            __ATOMIC_RELAXED, __HIP_MEMORY_SCOPE_AGENT);
        u[p ^ 1][512 + jg] = hnew;
      }

      if (t + 1 < C) {                 // h1[t+1] from L1 (usually already there)
        unsigned long long vv;
        do {
          vv = __hip_atomic_load(&ring1[(size_t)(t + 1) * HDIM + tid],
                                 __ATOMIC_RELAXED, __HIP_MEMORY_SCOPE_AGENT);
        } while ((unsigned)(vv >> 32) != tag + 1u);
        u[p ^ 1][tid] = __uint_as_float((unsigned)vv);
      }
      if (tid < HDIM - S2) {           // peers' h2[t]
        unsigned long long vv;
        do {
          vv = __hip_atomic_load(&ring2[(size_t)((t & (RING2-1)) << 9) + pm2],
                                 __ATOMIC_RELAXED, __HIP_MEMORY_SCOPE_AGENT);
        } while ((unsigned)(vv >> 32) != tag);
        u[p ^ 1][512 + pm2] = __uint_as_float((unsigned)vv);
      }
      __syncthreads();
      p ^= 1;
    }
  }
}

// ---------------------------------------------------------------------------
extern "C" void kernel_launch(void* const* d_in, const int* in_sizes, int n_in,
                              void* d_out, int out_size, void* d_ws, size_t ws_size,
                              hipStream_t stream) {
  const float* xs    = (const float*)d_in[0];
  const float* W_ih0 = (const float*)d_in[1];
  const float* W_hh0 = (const float*)d_in[2];
  const float* b0    = (const float*)d_in[3];
  const float* bn0   = (const float*)d_in[4];
  const float* W_ih1 = (const float*)d_in[5];
  const float* W_hh1 = (const float*)d_in[6];
  const float* b1    = (const float*)d_in[7];
  const float* bn1   = (const float*)d_in[8];
  const float* W_lin = (const float*)d_in[9];
  const float* b_lin = (const float*)d_in[10];
  float* out = (float*)d_out;

  // ws layout per chunk of C steps:
  //   ig0[C*1536] f32 | h2c[C*512] f32 | ring1[C*512] u64 | ring2[4*512] u64
  //   | h1carry[512] f32
  const size_t TAIL = (size_t)RING2 * HDIM * 8 + HDIM * 4;   // 18 KB
  int C = TSTEPS;
  while (C > 256 && (size_t)C * 12288 + TAIL > ws_size) C >>= 1;
  if ((size_t)C * 12288 + TAIL > ws_size) return;

  char* ws = (char*)d_ws;
  float*              igb = (float*)(ws);
  float*              h2c = (float*)(ws + (size_t)C * 6144);
  unsigned long long* r1  = (unsigned long long*)(ws + (size_t)C * 8192);
  unsigned long long* r2  = (unsigned long long*)(ws + (size_t)C * 12288);
  float*              h1c = (float*)(ws + (size_t)C * 12288 + RING2 * HDIM * 8);

  // Insurance: tags must start != any t0+t+1 (0xAA poison already can't match).
  hipMemsetAsync(r1, 0, (size_t)C * HDIM * 8 + RING2 * HDIM * 8, stream);

  const int nchunk = TSTEPS / C;
  for (int c = 0; c < nchunk; ++c) {
    const size_t t0 = (size_t)c * C;
    const int first = (c == 0);
    // igates0 = xs[t0:t0+C] @ W_ih0^T + b0     [C x 1536], K=128
    gemm_tn<128><<<dim3(C/128, G3/64), 256, 0, stream>>>(
        xs + t0 * 128, W_ih0, b0, igb, G3);
    // fused pipelined 2-layer scan chunk -> h2c
    gru2_scan<<<NB1 + NB2, 512, 0, stream>>>(
        igb, W_hh0, bn0, W_ih1, W_hh1, b1, bn1, h1c, h2c,
        r1, r2, C, (unsigned)t0, first);
    // out chunk = h2c @ W_lin^T + b_lin        [C x 128], K=512
    gemm_tn<512><<<dim3(C/128, 128/64), 256, 0, stream>>>(
        h2c, W_lin, b_lin, out + t0 * 128, 128);
  }
}

// Round 8
// 66346.631 us; speedup vs baseline: 1.0197x; 1.0197x over previous
//
#include <hip/hip_runtime.h>
#include <math.h>

// GRU RNN: T=32768, 2 layers H=512, in=128, out=128, fp32.
// v8 = v6 (fused 2-layer pipelined 48-block persistent scan, PASSED 67.7ms)
//      + interleaved L2 polls ONLY.
// v7 post-mortem: bundled (a) interleaved polls and (b) a one-step h1[t+2]
// register-prefetch pipeline; it diverged post-timing (race) and was 24%
// slower. The genuinely new dataflow was (b) (defer-use + dependence on L1
// being >=2 steps ahead). v8 keeps the v6 protocol EXACTLY -- same rows
// (ring1[t+1], ring2[t]), same tags, validated-then-immediately-used -- and
// only interleaves the two spin loops so both cross-XCD round trips are in
// flight together: tail = max(lat1,lat2) instead of lat1+lat2.
// Structure:
//   L1: 16 blocks x 32 rows, k=512; L2: 32 blocks x 16 rows, k=1024 (concat
//   [h1[t] || h2[t-1]]; folds the former igates1 GEMM into the scan).
//   ring1 full-chunk tagged (no wraparound); ring2 depth-4 tagged.
//   Per chunk: ig0 GEMM -> fused scan -> out GEMM.

#define TSTEPS 32768
#define HDIM   512
#define G3     1536
#define NB1    16          // layer-1 blocks
#define NB2    32          // layer-2 blocks
#define S1     32          // rows per L1 block
#define S2     16          // rows per L2 block
#define RING2  4

// Call-free gate functions (saturation-safe at +/-inf, no NaN):
__device__ __forceinline__ float sigf(float x) {
  return 1.f / (1.f + __expf(-x));
}
__device__ __forceinline__ float tanhfast(float x) {
  const float E = __expf(2.f * x);        // inf -> 1-0=1 ; 0 -> 1-2=-1
  return 1.f - 2.f / (E + 1.f);
}
// Pin a float4 in VGPRs (kept from v5 baseline; harmless).
__device__ __forceinline__ void pin4(float4& v) {
  asm volatile("" : "+v"(v.x), "+v"(v.y), "+v"(v.z), "+v"(v.w));
}

// ---------------------------------------------------------------------------
// GEMM: C[M,N] = A[M,K] * B[N,K]^T + bias[N].  BM=128 BN=64 BK=16, 256 thr.
// ---------------------------------------------------------------------------
template<int K>
__global__ __launch_bounds__(256)
void gemm_tn(const float* __restrict__ A, const float* __restrict__ B,
             const float* __restrict__ bias, float* __restrict__ C, int N) {
  __shared__ float As[16][128];
  __shared__ float Bs[16][64];
  const int bm  = blockIdx.x * 128;
  const int bn  = blockIdx.y * 64;
  const int tid = threadIdx.x;
  const int tx  = tid & 15;
  const int ty  = tid >> 4;
  const int lr  = tid >> 2;
  const int lk  = tid & 3;

  float acc[8][4];
#pragma unroll
  for (int i = 0; i < 8; ++i)
#pragma unroll
    for (int jj = 0; jj < 4; ++jj) acc[i][jj] = 0.f;

  for (int k0 = 0; k0 < K; k0 += 16) {
    float4 a0 = *(const float4*)&A[(size_t)(bm + lr) * K + k0 + lk * 4];
    float4 a1 = *(const float4*)&A[(size_t)(bm + lr + 64) * K + k0 + lk * 4];
    float4 bb = *(const float4*)&B[(size_t)(bn + lr) * K + k0 + lk * 4];
    __syncthreads();
    As[lk*4+0][lr]    = a0.x; As[lk*4+1][lr]    = a0.y;
    As[lk*4+2][lr]    = a0.z; As[lk*4+3][lr]    = a0.w;
    As[lk*4+0][lr+64] = a1.x; As[lk*4+1][lr+64] = a1.y;
    As[lk*4+2][lr+64] = a1.z; As[lk*4+3][lr+64] = a1.w;
    Bs[lk*4+0][lr] = bb.x; Bs[lk*4+1][lr] = bb.y;
    Bs[lk*4+2][lr] = bb.z; Bs[lk*4+3][lr] = bb.w;
    __syncthreads();
#pragma unroll
    for (int kk = 0; kk < 16; ++kk) {
      float4 b4  = *(const float4*)&Bs[kk][tx*4];
      float4 av0 = *(const float4*)&As[kk][ty*8];
      float4 av1 = *(const float4*)&As[kk][ty*8+4];
      float av[8] = {av0.x,av0.y,av0.z,av0.w,av1.x,av1.y,av1.z,av1.w};
#pragma unroll
      for (int i = 0; i < 8; ++i) {
        acc[i][0] += av[i]*b4.x; acc[i][1] += av[i]*b4.y;
        acc[i][2] += av[i]*b4.z; acc[i][3] += av[i]*b4.w;
      }
    }
  }
  float4 bv = *(const float4*)&bias[bn + tx*4];
#pragma unroll
  for (int i = 0; i < 8; ++i) {
    float4 o;
    o.x = acc[i][0] + bv.x; o.y = acc[i][1] + bv.y;
    o.z = acc[i][2] + bv.z; o.w = acc[i][3] + bv.w;
    *(float4*)&C[(size_t)(bm + ty*8 + i) * N + bn + tx*4] = o;
  }
}

// ---------------------------------------------------------------------------
// Fused 2-layer pipelined scan. Grid = NB1 + NB2 = 48 blocks x 512 threads.
// ---------------------------------------------------------------------------
__global__ __launch_bounds__(512, 2)
void gru2_scan(const float* __restrict__ ig0,   // [C][1536] layer-1 igates
               const float* __restrict__ Whh0,  // [1536][512]
               const float* __restrict__ bn0,   // [512]
               const float* __restrict__ Wih1,  // [1536][512]
               const float* __restrict__ Whh1,  // [1536][512]
               const float* __restrict__ b1v,   // [1536]
               const float* __restrict__ bn1,   // [512]
               float* __restrict__ h1carry,     // [512] cross-chunk carry
               float* __restrict__ h2c,         // [C][512] layer-2 history
               unsigned long long* __restrict__ ring1, // [C][512]
               unsigned long long* __restrict__ ring2, // [RING2][512]
               int C, unsigned t0, int first)
{
  const int tid = threadIdx.x;
  __shared__ __align__(16) float u[2][1024];   // L1 uses [.][0..511]
  __shared__ float igl[2][96];

  if (blockIdx.x < NB1) {
    // =================== layer 1 (identical to v6) ===================
    const int b  = blockIdx.x;
    const int j  = tid >> 4;        // 0..31 row in slice
    const int g  = tid & 15;        // k-group (32 floats)
    const int jg = b * S1 + j;
    float4 wr[8], wz[8], wn[8];
    {
      const float* Wr = Whh0 + (size_t)jg            * HDIM + g * 32;
      const float* Wz = Whh0 + (size_t)(HDIM  + jg)  * HDIM + g * 32;
      const float* Wn = Whh0 + (size_t)(2*HDIM + jg) * HDIM + g * 32;
#pragma unroll
      for (int i = 0; i < 8; ++i) {
        const int c = (i + g) & 7;            // rotation: 2-way banks (free)
        wr[i] = *(const float4*)(Wr + c * 4);
        wz[i] = *(const float4*)(Wz + c * 4);
        wn[i] = *(const float4*)(Wn + c * 4);
      }
    }
#pragma unroll
    for (int i = 0; i < 8; ++i) { pin4(wr[i]); pin4(wz[i]); pin4(wn[i]); }
    const float bnj = bn0[jg];
    u[0][tid] = first ? 0.f : h1carry[tid];
    if (tid < 96)
      igl[0][tid] = ig0[(size_t)(tid >> 5) * HDIM + b * S1 + (tid & 31)];
    const int pm = (tid < b * S1) ? tid : tid + S1;   // 480 pollers
    __syncthreads();

    int p = 0;
    for (int t = 0; t < C; ++t) {
      float pfn = 0.f;
      if (tid < 96 && t + 1 < C)
        pfn = ig0[(size_t)(t + 1) * G3 + (size_t)(tid >> 5) * HDIM
                  + b * S1 + (tid & 31)];

      const float4* h4 = (const float4*)u[p];
      float4 ar = make_float4(0,0,0,0), az = make_float4(0,0,0,0),
             an = make_float4(0,0,0,0);
#pragma unroll
      for (int i = 0; i < 8; ++i) {
        const int c = (i + g) & 7;
        const float4 hv = h4[g * 8 + c];
        ar.x += wr[i].x*hv.x; ar.y += wr[i].y*hv.y; ar.z += wr[i].z*hv.z; ar.w += wr[i].w*hv.w;
        az.x += wz[i].x*hv.x; az.y += wz[i].y*hv.y; az.z += wz[i].z*hv.z; az.w += wz[i].w*hv.w;
        an.x += wn[i].x*hv.x; an.y += wn[i].y*hv.y; an.z += wn[i].z*hv.z; an.w += wn[i].w*hv.w;
      }
      float sr = (ar.x + ar.y) + (ar.z + ar.w);
      float sz = (az.x + az.y) + (az.z + az.w);
      float sn = (an.x + an.y) + (an.z + an.w);
      sr += __shfl_xor(sr,1); sr += __shfl_xor(sr,2); sr += __shfl_xor(sr,4); sr += __shfl_xor(sr,8);
      sz += __shfl_xor(sz,1); sz += __shfl_xor(sz,2); sz += __shfl_xor(sz,4); sz += __shfl_xor(sz,8);
      sn += __shfl_xor(sn,1); sn += __shfl_xor(sn,2); sn += __shfl_xor(sn,4); sn += __shfl_xor(sn,8);

      const unsigned tag = t0 + (unsigned)t + 1u;
      if (g == 0) {
        const float* igc = igl[t & 1];
        const float r = sigf(igc[j]      + sr);
        const float z = sigf(igc[32 + j] + sz);
        const float n = tanhfast(igc[64 + j] + r * (sn + bnj));
        const float hnew = n + z * (u[p][jg] - n);
        __hip_atomic_store(&ring1[(size_t)t * HDIM + jg],
            ((unsigned long long)tag << 32) | (unsigned)__float_as_uint(hnew),
            __ATOMIC_RELAXED, __HIP_MEMORY_SCOPE_AGENT);
        u[p ^ 1][jg] = hnew;
        if (t == C - 1) h1carry[jg] = hnew;
      }
      if (tid < 96 && t + 1 < C) igl[(t + 1) & 1][tid] = pfn;

      if (tid < HDIM - S1) {                    // gather peers' h1[t]
        unsigned long long vv;
        do {
          vv = __hip_atomic_load(&ring1[(size_t)t * HDIM + pm],
                                 __ATOMIC_RELAXED, __HIP_MEMORY_SCOPE_AGENT);
        } while ((unsigned)(vv >> 32) != tag);
        u[p ^ 1][pm] = __uint_as_float((unsigned)vv);
      }
      __syncthreads();
      p ^= 1;
    }
  } else {
    // =================== layer 2 (v6 protocol, polls interleaved) ========
    const int b  = blockIdx.x - NB1;
    const int j  = tid >> 5;        // 0..15 row in slice
    const int g  = tid & 31;        // k-group (32 of 1024 floats)
    const int jg = b * S2 + j;
    float4 wr[8], wz[8], wn[8];
    {
      const float* base = (g < 16) ? Wih1 : Whh1;   // concat [h1 || h2] k-split
      const int gk = (g & 15) * 32;
      const float* Wr = base + (size_t)jg            * HDIM + gk;
      const float* Wz = base + (size_t)(HDIM  + jg)  * HDIM + gk;
      const float* Wn = base + (size_t)(2*HDIM + jg) * HDIM + gk;
#pragma unroll
      for (int i = 0; i < 8; ++i) {
        const int c = (i + g) & 7;
        wr[i] = *(const float4*)(Wr + c * 4);
        wz[i] = *(const float4*)(Wz + c * 4);
        wn[i] = *(const float4*)(Wn + c * 4);
      }
    }
#pragma unroll
    for (int i = 0; i < 8; ++i) { pin4(wr[i]); pin4(wz[i]); pin4(wn[i]); }
    const float b1r = b1v[jg], b1z = b1v[HDIM + jg], b1n = b1v[2*HDIM + jg];
    const float bnj = bn1[jg];

    // init: u[0] = [h1[0] (poll) || h2 carry]   (exactly v6)
    u[0][512 + tid] = first ? 0.f : h2c[(size_t)(C - 1) * HDIM + tid];
    {
      unsigned long long vv;
      do {
        vv = __hip_atomic_load(&ring1[tid], __ATOMIC_RELAXED,
                               __HIP_MEMORY_SCOPE_AGENT);
      } while ((unsigned)(vv >> 32) != t0 + 1u);
      u[0][tid] = __uint_as_float((unsigned)vv);
    }
    const int pm2 = (tid < b * S2) ? tid : tid + S2;  // 496 pollers
    __syncthreads();

    int p = 0;
    for (int t = 0; t < C; ++t) {
      const float4* u4 = (const float4*)u[p];
      float4 ar = make_float4(0,0,0,0), az = make_float4(0,0,0,0),
             an = make_float4(0,0,0,0);
#pragma unroll
      for (int i = 0; i < 8; ++i) {
        const int c = (i + g) & 7;
        const float4 hv = u4[g * 8 + c];
        ar.x += wr[i].x*hv.x; ar.y += wr[i].y*hv.y; ar.z += wr[i].z*hv.z; ar.w += wr[i].w*hv.w;
        az.x += wz[i].x*hv.x; az.y += wz[i].y*hv.y; az.z += wz[i].z*hv.z; az.w += wz[i].w*hv.w;
        an.x += wn[i].x*hv.x; an.y += wn[i].y*hv.y; an.z += wn[i].z*hv.z; an.w += wn[i].w*hv.w;
      }
      float sr = (ar.x + ar.y) + (ar.z + ar.w);
      float sz = (az.x + az.y) + (az.z + az.w);
      float sn = (an.x + an.y) + (an.z + an.w);
      // r,z: full 32-lane sum. n: keep ih half (g<16) and hh half separate.
      sr += __shfl_xor(sr,1); sr += __shfl_xor(sr,2); sr += __shfl_xor(sr,4); sr += __shfl_xor(sr,8);
      sz += __shfl_xor(sz,1); sz += __shfl_xor(sz,2); sz += __shfl_xor(sz,4); sz += __shfl_xor(sz,8);
      sn += __shfl_xor(sn,1); sn += __shfl_xor(sn,2); sn += __shfl_xor(sn,4); sn += __shfl_xor(sn,8);
      sr += __shfl_xor(sr, 16);
      sz += __shfl_xor(sz, 16);
      const float snb = __shfl_xor(sn, 16);   // at g==0: hh-half sum

      const unsigned tag = t0 + (unsigned)t + 1u;
      if (g == 0) {
        const float r = sigf(sr + b1r);
        const float z = sigf(sz + b1z);
        const float n = tanhfast((sn + b1n) + r * (snb + bnj));
        const float hnew = n + z * (u[p][512 + jg] - n);
        h2c[(size_t)t * HDIM + jg] = hnew;
        __hip_atomic_store(&ring2[(size_t)((t & (RING2-1)) << 9) + jg],
            ((unsigned long long)tag << 32) | (unsigned)__float_as_uint(hnew),
            __ATOMIC_RELAXED, __HIP_MEMORY_SCOPE_AGENT);
        u[p ^ 1][512 + jg] = hnew;
      }

      // v6's two polls (h1[t+1] -> u[p^1][tid]; peers' h2[t] ->
      // u[p^1][512+pm2]) with IDENTICAL rows/tags/writes, interleaved in one
      // retry loop so both cross-XCD round trips are in flight concurrently.
      {
        bool n1 = (t + 1 < C);
        bool n2 = (tid < HDIM - S2);
        const size_t i1 = (size_t)(t + 1) * HDIM + tid;
        const size_t i2 = (size_t)((t & (RING2-1)) << 9) + pm2;
        while (n1 || n2) {
          unsigned long long v1 = 0, v2 = 0;
          if (n1) v1 = __hip_atomic_load(&ring1[i1], __ATOMIC_RELAXED,
                                         __HIP_MEMORY_SCOPE_AGENT);
          if (n2) v2 = __hip_atomic_load(&ring2[i2], __ATOMIC_RELAXED,
                                         __HIP_MEMORY_SCOPE_AGENT);
          if (n1 && (unsigned)(v1 >> 32) == tag + 1u) {
            u[p ^ 1][tid] = __uint_as_float((unsigned)v1);
            n1 = false;
          }
          if (n2 && (unsigned)(v2 >> 32) == tag) {
            u[p ^ 1][512 + pm2] = __uint_as_float((unsigned)v2);
            n2 = false;
          }
        }
      }
      __syncthreads();
      p ^= 1;
    }
  }
}

// ---------------------------------------------------------------------------
extern "C" void kernel_launch(void* const* d_in, const int* in_sizes, int n_in,
                              void* d_out, int out_size, void* d_ws, size_t ws_size,
                              hipStream_t stream) {
  const float* xs    = (const float*)d_in[0];
  const float* W_ih0 = (const float*)d_in[1];
  const float* W_hh0 = (const float*)d_in[2];
  const float* b0    = (const float*)d_in[3];
  const float* bn0   = (const float*)d_in[4];
  const float* W_ih1 = (const float*)d_in[5];
  const float* W_hh1 = (const float*)d_in[6];
  const float* b1    = (const float*)d_in[7];
  const float* bn1   = (const float*)d_in[8];
  const float* W_lin = (const float*)d_in[9];
  const float* b_lin = (const float*)d_in[10];
  float* out = (float*)d_out;

  // ws layout per chunk of C steps:
  //   ig0[C*1536] f32 | h2c[C*512] f32 | ring1[C*512] u64 | ring2[4*512] u64
  //   | h1carry[512] f32
  const size_t TAIL = (size_t)RING2 * HDIM * 8 + HDIM * 4;   // 18 KB
  int C = TSTEPS;
  while (C > 256 && (size_t)C * 12288 + TAIL > ws_size) C >>= 1;
  if ((size_t)C * 12288 + TAIL > ws_size) return;

  char* ws = (char*)d_ws;
  float*              igb = (float*)(ws);
  float*              h2c = (float*)(ws + (size_t)C * 6144);
  unsigned long long* r1  = (unsigned long long*)(ws + (size_t)C * 8192);
  unsigned long long* r2  = (unsigned long long*)(ws + (size_t)C * 12288);
  float*              h1c = (float*)(ws + (size_t)C * 12288 + RING2 * HDIM * 8);

  // Insurance: tags must start != any t0+t+1 (0xAA poison already can't match).
  hipMemsetAsync(r1, 0, (size_t)C * HDIM * 8 + RING2 * HDIM * 8, stream);

  const int nchunk = TSTEPS / C;
  for (int c = 0; c < nchunk; ++c) {
    const size_t t0 = (size_t)c * C;
    const int first = (c == 0);
    // igates0 = xs[t0:t0+C] @ W_ih0^T + b0     [C x 1536], K=128
    gemm_tn<128><<<dim3(C/128, G3/64), 256, 0, stream>>>(
        xs + t0 * 128, W_ih0, b0, igb, G3);
    // fused pipelined 2-layer scan chunk -> h2c
    gru2_scan<<<NB1 + NB2, 512, 0, stream>>>(
        igb, W_hh0, bn0, W_ih1, W_hh1, b1, bn1, h1c, h2c,
        r1, r2, C, (unsigned)t0, first);
    // out chunk = h2c @ W_lin^T + b_lin        [C x 128], K=512
    gemm_tn<512><<<dim3(C/128, 128/64), 256, 0, stream>>>(
        h2c, W_lin, b_lin, out + t0 * 128, 128);
  }
}